// Round 9
// baseline (7172.331 us; speedup 1.0000x reference)
//
#include <hip/hip_runtime.h>

// LSTM: B=512, T=1024, D=64, H=128, gates=4H=512, fc head H->64->1.
//
// Rounds 1-8 lesson: the compiler rematerializes loop-invariant weight
// loads into the t-loop no matter what (launch_bounds, pre-loop pins,
// loop-carried pins) -- pins move together with their def chain. VGPR_Count
// was always < weights+working set and per-step time matched the VMEM-issue
// cost of rebuilding fragments from L2 (~3000 cyc/step in r8).
//
// THIS ROUND: weights are staged through LDS that is CLOBBERED by the
// t-loop (the gl gate buffer). global->f16->LDS -> barrier -> ds_read_b128
// fragments -> barrier -> loop rewrites the buffer. The register copy
// becomes the only copy: remat is illegal, and with launch_bounds(512,1)
// (512-VGPR budget, ~160 live) there is no spill pressure either.
//
// 32 blocks x 512 threads (8 waves), block owns 16 batch rows.
// Per step: gates[16,512] = [h|x][16,192] @ W^T via v_mfma_f32_16x16x32_f16.
// Wave w owns gates [64w,64w+64) = 4 N-tiles x 6 K-tiles = 24 MFMA/step.
// D stored transposed (gl[gate][row], one b128); cell reads 4 rows/gate as
// one b128; c[4] in registers. 2 barriers/step.

#define TT 1024
#define DD 64
#define HH 128
#define ROWS 16
#define PROW 200    // hx row stride in f16 (400 B, 16B-aligned)
#define GROW 20     // gl row stride in f32 (16 rows + 4 pad)

typedef _Float16 f16x8 __attribute__((ext_vector_type(8)));
typedef float f32x4 __attribute__((ext_vector_type(4)));

__device__ __forceinline__ float sigm(float x) {
    return 1.f / (1.f + __expf(-x));
}
__device__ __forceinline__ float tanh_f(float x) {
    return 1.f - 2.f / (__expf(2.f * x) + 1.f);
}

__global__ __launch_bounds__(512, 1)
void lstm_mfma_kernel(const float* __restrict__ x_seq,
                      const float* __restrict__ W_ih,
                      const float* __restrict__ W_hh,
                      const float* __restrict__ b_ih,
                      const float* __restrict__ b_hh,
                      const float* __restrict__ W1v,
                      const float* __restrict__ b1v,
                      const float* __restrict__ W2v,
                      const float* __restrict__ b2v,
                      float* __restrict__ out)
{
    const int tid  = threadIdx.x;
    const int lane = tid & 63;
    const int w    = tid >> 6;        // wave 0..7
    const int p    = lane >> 4;       // k-group 0..3
    const int cc   = lane & 15;       // col (B/D) / row (A) within tile
    const int b0   = blockIdx.x * ROWS;

    __shared__ __align__(16) _Float16 hx[2][ROWS][PROW];  // [buf][row][h|x]
    __shared__ __align__(16) float    gl[512][GROW];      // [gate][row] f32

    // ================= weight staging through clobbered LDS ==============
    // wstage aliases gl (40 KB >= 32 KB). The t-loop rewrites gl every step,
    // so the fragment registers read from it CANNOT be rematerialized.
    _Float16* wstage = reinterpret_cast<_Float16*>(&gl[0][0]); // [512][32]

    f16x8 bf[4][6];
#pragma unroll 1
    for (int g = 0; g < 6; ++g) {
        // cooperative: thread tid converts gate row tid, k in [32g, 32g+32)
        const float* srcrow = (g < 4) ? (W_hh + tid * HH + 32 * g)
                                      : (W_ih + tid * DD + 32 * (g - 4));
        const float4* s4 = reinterpret_cast<const float4*>(srcrow);
        _Float16* dst = wstage + tid * 32;
#pragma unroll
        for (int c = 0; c < 4; ++c) {
            const float4 lo = s4[2 * c], hi = s4[2 * c + 1];
            f16x8 f;
            f[0] = (_Float16)lo.x; f[1] = (_Float16)lo.y;
            f[2] = (_Float16)lo.z; f[3] = (_Float16)lo.w;
            f[4] = (_Float16)hi.x; f[5] = (_Float16)hi.y;
            f[6] = (_Float16)hi.z; f[7] = (_Float16)hi.w;
            *reinterpret_cast<f16x8*>(dst + 8 * c) = f;
        }
        __syncthreads();
        // fragment read: bf[nt][g] = W[gate=64w+16nt+cc][k=32g+8p+j]
#pragma unroll
        for (int nt = 0; nt < 4; ++nt) {
            const int gate = 64 * w + 16 * nt + cc;
            bf[nt][g] =
                *reinterpret_cast<const f16x8*>(wstage + gate * 32 + 8 * p);
        }
        __syncthreads();
    }

    // bias staging through the same clobbered region
    float bias[4];
    {
        float* bstage = reinterpret_cast<float*>(&gl[0][0]);  // [512]
        bstage[tid] = b_ih[tid] + b_hh[tid];
        __syncthreads();
#pragma unroll
        for (int nt = 0; nt < 4; ++nt)
            bias[nt] = bstage[64 * w + 16 * nt + cc];
        __syncthreads();
    }
    // =====================================================================

    // ---- cell ownership: unit u, rows 4qd..4qd+3 ----
    const int u  = tid & 127;
    const int qd = tid >> 7;
    float c0 = 0.f, c1 = 0.f, c2 = 0.f, c3 = 0.f;

    // ---- init: h = 0 (2048 cells), x(0) (1024 elems) ----
#pragma unroll
    for (int i = 0; i < 4; ++i) {
        const int idx = tid + 512 * i;
        hx[0][idx >> 7][idx & 127] = (_Float16)0.f;
    }
    {
        const int xr = tid >> 6, xk = tid & 63;
        hx[0][xr][HH + xk]     = (_Float16)x_seq[((b0 + xr) * TT) * DD + xk];
        hx[0][xr + 8][HH + xk] = (_Float16)x_seq[((b0 + xr + 8) * TT) * DD + xk];
    }
    __syncthreads();

    const int xr = tid >> 6, xk = tid & 63;   // x-prefetch coords

    for (int t = 0; t < TT; ++t) {
        const int cur = t & 1, nxt = cur ^ 1;

        // prefetch x(t+1) early (coalesced); hides under the MFMA phase
        float xp0 = 0.f, xp1 = 0.f;
        const bool pre = (t + 1 < TT);
        if (pre) {
            xp0 = x_seq[((b0 + xr) * TT + (t + 1)) * DD + xk];
            xp1 = x_seq[((b0 + xr + 8) * TT + (t + 1)) * DD + xk];
        }

        // ---- A-fragments: row cc, k-slice 32g+8p (shared by 4 N-tiles) ----
        f16x8 a[6];
#pragma unroll
        for (int g = 0; g < 6; ++g)
            a[g] = *reinterpret_cast<const f16x8*>(&hx[cur][cc][32 * g + 8 * p]);

        // ---- 4 interleaved MFMA chains, bias folded into acc init ----
        f32x4 acc[4];
#pragma unroll
        for (int nt = 0; nt < 4; ++nt)
            acc[nt] = (f32x4){bias[nt], bias[nt], bias[nt], bias[nt]};
#pragma unroll
        for (int g = 0; g < 6; ++g)
#pragma unroll
            for (int nt = 0; nt < 4; ++nt)
                acc[nt] = __builtin_amdgcn_mfma_f32_16x16x32_f16(
                    a[g], bf[nt][g], acc[nt], 0, 0, 0);

        // ---- transposed store: acc[j] = row 4p+j of gate 64w+16nt+cc ----
#pragma unroll
        for (int nt = 0; nt < 4; ++nt)
            *reinterpret_cast<f32x4*>(&gl[64 * w + 16 * nt + cc][4 * p]) =
                acc[nt];
        __syncthreads();

        // ---- cell: unit u, rows 4qd..4qd+3, one b128 per gate class ----
        {
            const f32x4 gi = *reinterpret_cast<const f32x4*>(&gl[u][4 * qd]);
            const f32x4 gf =
                *reinterpret_cast<const f32x4*>(&gl[u + 128][4 * qd]);
            const f32x4 gg =
                *reinterpret_cast<const f32x4*>(&gl[u + 256][4 * qd]);
            const f32x4 go =
                *reinterpret_cast<const f32x4*>(&gl[u + 384][4 * qd]);

            c0 = sigm(gf[0]) * c0 + sigm(gi[0]) * tanh_f(gg[0]);
            c1 = sigm(gf[1]) * c1 + sigm(gi[1]) * tanh_f(gg[1]);
            c2 = sigm(gf[2]) * c2 + sigm(gi[2]) * tanh_f(gg[2]);
            c3 = sigm(gf[3]) * c3 + sigm(gi[3]) * tanh_f(gg[3]);
            hx[nxt][4 * qd + 0][u] = (_Float16)(sigm(go[0]) * tanh_f(c0));
            hx[nxt][4 * qd + 1][u] = (_Float16)(sigm(go[1]) * tanh_f(c1));
            hx[nxt][4 * qd + 2][u] = (_Float16)(sigm(go[2]) * tanh_f(c2));
            hx[nxt][4 * qd + 3][u] = (_Float16)(sigm(go[3]) * tanh_f(c3));
        }
        if (pre) {
            hx[nxt][xr][HH + xk]     = (_Float16)xp0;
            hx[nxt][xr + 8][HH + xk] = (_Float16)xp1;
        }
        __syncthreads();
    }

    // ---- fused head: wave w -> rows 2w, 2w+1; lane = fc1 unit ----
#pragma unroll
    for (int rr = 0; rr < 2; ++rr) {
        const int r = 2 * w + rr;
        float z = b1v[lane];
        const float* w1 = W1v + lane * HH;
#pragma unroll 16
        for (int k = 0; k < HH; ++k)
            z = fmaf(w1[k], (float)hx[0][r][k], z);
        z = fmaxf(z, 0.f) * W2v[lane];
#pragma unroll
        for (int off = 32; off; off >>= 1)
            z += __shfl_down(z, off, 64);
        if (lane == 0) out[b0 + r] = z + b2v[0];
    }
}

extern "C" void kernel_launch(void* const* d_in, const int* in_sizes, int n_in,
                              void* d_out, int out_size, void* d_ws, size_t ws_size,
                              hipStream_t stream) {
    const float* x_seq = (const float*)d_in[0];
    const float* W_ih  = (const float*)d_in[1];
    const float* W_hh  = (const float*)d_in[2];
    const float* b_ih  = (const float*)d_in[3];
    const float* b_hh  = (const float*)d_in[4];
    const float* W1    = (const float*)d_in[5];
    const float* b1    = (const float*)d_in[6];
    const float* W2    = (const float*)d_in[7];
    const float* b2    = (const float*)d_in[8];
    float* out = (float*)d_out;

    lstm_mfma_kernel<<<32, 512, 0, stream>>>(
        x_seq, W_ih, W_hh, b_ih, b_hh, W1, b1, W2, b2, out);
}

// Round 10
// 1927.913 us; speedup vs baseline: 3.7203x; 3.7203x over previous
//
#include <hip/hip_runtime.h>

// LSTM: B=512, T=1024, D=64, H=128, gates=4H=512, fc head H->64->1.
//
// Residency war history:
//  r2-r7: compiler SINKS loop-invariant weight-load chains into the t-loop
//         (remat from L2 every step). Pins don't help (they move with defs).
//  r8:    same, ~3000 cyc/step of VMEM issue rebuilding fragments.
//  r9:    LDS-clobber staging was right, but '#pragma unroll 1' made bf[]
//         runtime-indexed -> scratch from birth (rule #20): WRITE_SIZE 6 MB
//         = 16K threads x 384 B. Never actually tested the mechanism.
//  r10 (this): (a) staging fully unrolled (static indices); (b) fragments
//         read from LDS that the t-loop CLOBBERS (gl) -> remat illegal;
//         (c) fragments homed in AGPRs via inline-asm MFMA "a" constraint +
//         one-time "+a" class steer; (d) amdgpu_waves_per_eu(2,2) declares
//         the true occupancy (8-wave block, 1 block/CU) -> 256-reg budget.
//
// 32 blocks x 512 threads (8 waves), block owns 16 batch rows.
// Per step: gates[16,512] = [h|x][16,192] @ W^T via v_mfma_f32_16x16x32_f16.
// Wave w owns gates [64w,64w+64) = 4 N-tiles x 6 K-tiles = 24 MFMA/step.
// D stored transposed (gl[gate][row], one b128); cell reads 4 rows/gate as
// one b128; c[4] in registers. 2 barriers/step.

#define TT 1024
#define DD 64
#define HH 128
#define ROWS 16
#define PROW 200    // hx row stride in f16 (400 B, 16B-aligned)
#define GROW 20     // gl row stride in f32 (16 rows + 4 pad)

typedef _Float16 f16x8 __attribute__((ext_vector_type(8)));
typedef float f32x4 __attribute__((ext_vector_type(4)));

// D = A*B + D, with the B fragment (weights) homed in AGPRs.
__device__ __forceinline__ void mfma_ab(f16x8 a, f16x8 b, f32x4& c) {
    asm("v_mfma_f32_16x16x32_f16 %0, %1, %2, %0"
        : "+v"(c)
        : "v"(a), "a"(b));
}

__device__ __forceinline__ float sigm(float x) {
    return 1.f / (1.f + __expf(-x));
}
__device__ __forceinline__ float tanh_f(float x) {
    return 1.f - 2.f / (__expf(2.f * x) + 1.f);
}

__global__ __launch_bounds__(512)
__attribute__((amdgpu_waves_per_eu(2, 2)))
void lstm_mfma_kernel(const float* __restrict__ x_seq,
                      const float* __restrict__ W_ih,
                      const float* __restrict__ W_hh,
                      const float* __restrict__ b_ih,
                      const float* __restrict__ b_hh,
                      const float* __restrict__ W1v,
                      const float* __restrict__ b1v,
                      const float* __restrict__ W2v,
                      const float* __restrict__ b2v,
                      float* __restrict__ out)
{
    const int tid  = threadIdx.x;
    const int lane = tid & 63;
    const int w    = tid >> 6;        // wave 0..7
    const int p    = lane >> 4;       // k-group 0..3
    const int cc   = lane & 15;       // col (B/D) / row (A) within tile
    const int b0   = blockIdx.x * ROWS;

    __shared__ __align__(16) _Float16 hx[2][ROWS][PROW];  // [buf][row][h|x]
    __shared__ __align__(16) float    gl[512][GROW];      // [gate][row] f32

    // ================= weight staging through clobbered LDS ==============
    // wstage aliases gl (40 KB >= 32 KB). The t-loop rewrites gl every
    // step, so fragment registers read from it cannot be rematerialized.
    _Float16* wstage = reinterpret_cast<_Float16*>(&gl[0][0]); // [512][32]

    f16x8 bf[4][6];
#pragma unroll
    for (int g = 0; g < 6; ++g) {       // FULLY unrolled: static indices
        // cooperative: thread tid converts gate row tid, k in [32g, 32g+32)
        const float* srcrow = (g < 4) ? (W_hh + tid * HH + 32 * g)
                                      : (W_ih + tid * DD + 32 * (g - 4));
        const float4* s4 = reinterpret_cast<const float4*>(srcrow);
        _Float16* dst = wstage + tid * 32;
#pragma unroll
        for (int c = 0; c < 4; ++c) {
            const float4 lo = s4[2 * c], hi = s4[2 * c + 1];
            f16x8 f;
            f[0] = (_Float16)lo.x; f[1] = (_Float16)lo.y;
            f[2] = (_Float16)lo.z; f[3] = (_Float16)lo.w;
            f[4] = (_Float16)hi.x; f[5] = (_Float16)hi.y;
            f[6] = (_Float16)hi.z; f[7] = (_Float16)hi.w;
            *reinterpret_cast<f16x8*>(dst + 8 * c) = f;
        }
        __syncthreads();
        // fragment read: bf[nt][g] = W[gate=64w+16nt+cc][k=32g+8p+j]
#pragma unroll
        for (int nt = 0; nt < 4; ++nt) {
            const int gate = 64 * w + 16 * nt + cc;
            bf[nt][g] =
                *reinterpret_cast<const f16x8*>(wstage + gate * 32 + 8 * p);
        }
        __syncthreads();
    }
    // one-time register-class steer: home the fragments in AGPRs
#pragma unroll
    for (int nt = 0; nt < 4; ++nt)
#pragma unroll
        for (int g = 0; g < 6; ++g)
            asm("" : "+a"(bf[nt][g]));

    // bias staging through the same clobbered region
    float bias[4];
    {
        float* bstage = reinterpret_cast<float*>(&gl[0][0]);  // [512]
        bstage[tid] = b_ih[tid] + b_hh[tid];
        __syncthreads();
#pragma unroll
        for (int nt = 0; nt < 4; ++nt)
            bias[nt] = bstage[64 * w + 16 * nt + cc];
        __syncthreads();
    }
    // =====================================================================

    // ---- cell ownership: unit u, rows 4qd..4qd+3 ----
    const int u  = tid & 127;
    const int qd = tid >> 7;
    float c0 = 0.f, c1 = 0.f, c2 = 0.f, c3 = 0.f;

    // ---- init: h = 0 (2048 cells), x(0) (1024 elems) ----
#pragma unroll
    for (int i = 0; i < 4; ++i) {
        const int idx = tid + 512 * i;
        hx[0][idx >> 7][idx & 127] = (_Float16)0.f;
    }
    {
        const int xr = tid >> 6, xk = tid & 63;
        hx[0][xr][HH + xk]     = (_Float16)x_seq[((b0 + xr) * TT) * DD + xk];
        hx[0][xr + 8][HH + xk] = (_Float16)x_seq[((b0 + xr + 8) * TT) * DD + xk];
    }
    __syncthreads();

    const int xr = tid >> 6, xk = tid & 63;   // x-prefetch coords

    for (int t = 0; t < TT; ++t) {
        const int cur = t & 1, nxt = cur ^ 1;

        // prefetch x(t+1) early (coalesced); hides under the MFMA phase
        float xp0 = 0.f, xp1 = 0.f;
        const bool pre = (t + 1 < TT);
        if (pre) {
            xp0 = x_seq[((b0 + xr) * TT + (t + 1)) * DD + xk];
            xp1 = x_seq[((b0 + xr + 8) * TT + (t + 1)) * DD + xk];
        }

        // ---- A-fragments: row cc, k-slice 32g+8p (shared by 4 N-tiles) ----
        f16x8 a[6];
#pragma unroll
        for (int g = 0; g < 6; ++g)
            a[g] = *reinterpret_cast<const f16x8*>(&hx[cur][cc][32 * g + 8 * p]);

        // ---- 4 interleaved MFMA chains, bias folded into acc init ----
        f32x4 acc[4];
#pragma unroll
        for (int nt = 0; nt < 4; ++nt)
            acc[nt] = (f32x4){bias[nt], bias[nt], bias[nt], bias[nt]};
#pragma unroll
        for (int g = 0; g < 6; ++g)
#pragma unroll
            for (int nt = 0; nt < 4; ++nt)
                mfma_ab(a[g], bf[nt][g], acc[nt]);

        // ---- transposed store: acc[j] = row 4p+j of gate 64w+16nt+cc ----
#pragma unroll
        for (int nt = 0; nt < 4; ++nt)
            *reinterpret_cast<f32x4*>(&gl[64 * w + 16 * nt + cc][4 * p]) =
                acc[nt];
        __syncthreads();

        // ---- cell: unit u, rows 4qd..4qd+3, one b128 per gate class ----
        {
            const f32x4 gi = *reinterpret_cast<const f32x4*>(&gl[u][4 * qd]);
            const f32x4 gf =
                *reinterpret_cast<const f32x4*>(&gl[u + 128][4 * qd]);
            const f32x4 gg =
                *reinterpret_cast<const f32x4*>(&gl[u + 256][4 * qd]);
            const f32x4 go =
                *reinterpret_cast<const f32x4*>(&gl[u + 384][4 * qd]);

            c0 = sigm(gf[0]) * c0 + sigm(gi[0]) * tanh_f(gg[0]);
            c1 = sigm(gf[1]) * c1 + sigm(gi[1]) * tanh_f(gg[1]);
            c2 = sigm(gf[2]) * c2 + sigm(gi[2]) * tanh_f(gg[2]);
            c3 = sigm(gf[3]) * c3 + sigm(gi[3]) * tanh_f(gg[3]);
            hx[nxt][4 * qd + 0][u] = (_Float16)(sigm(go[0]) * tanh_f(c0));
            hx[nxt][4 * qd + 1][u] = (_Float16)(sigm(go[1]) * tanh_f(c1));
            hx[nxt][4 * qd + 2][u] = (_Float16)(sigm(go[2]) * tanh_f(c2));
            hx[nxt][4 * qd + 3][u] = (_Float16)(sigm(go[3]) * tanh_f(c3));
        }
        if (pre) {
            hx[nxt][xr][HH + xk]     = (_Float16)xp0;
            hx[nxt][xr + 8][HH + xk] = (_Float16)xp1;
        }
        __syncthreads();
    }

    // ---- fused head: wave w -> rows 2w, 2w+1; lane = fc1 unit ----
#pragma unroll
    for (int rr = 0; rr < 2; ++rr) {
        const int r = 2 * w + rr;
        float z = b1v[lane];
        const float* w1 = W1v + lane * HH;
#pragma unroll 16
        for (int k = 0; k < HH; ++k)
            z = fmaf(w1[k], (float)hx[0][r][k], z);
        z = fmaxf(z, 0.f) * W2v[lane];
#pragma unroll
        for (int off = 32; off; off >>= 1)
            z += __shfl_down(z, off, 64);
        if (lane == 0) out[b0 + r] = z + b2v[0];
    }
}

extern "C" void kernel_launch(void* const* d_in, const int* in_sizes, int n_in,
                              void* d_out, int out_size, void* d_ws, size_t ws_size,
                              hipStream_t stream) {
    const float* x_seq = (const float*)d_in[0];
    const float* W_ih  = (const float*)d_in[1];
    const float* W_hh  = (const float*)d_in[2];
    const float* b_ih  = (const float*)d_in[3];
    const float* b_hh  = (const float*)d_in[4];
    const float* W1    = (const float*)d_in[5];
    const float* b1    = (const float*)d_in[6];
    const float* W2    = (const float*)d_in[7];
    const float* b2    = (const float*)d_in[8];
    float* out = (float*)d_out;

    lstm_mfma_kernel<<<32, 512, 0, stream>>>(
        x_seq, W_ih, W_hh, b_ih, b_hh, W1, b1, W2, b2, out);
}

// Round 11
// 1719.595 us; speedup vs baseline: 4.1709x; 1.1211x over previous
//
#include <hip/hip_runtime.h>

// LSTM: B=512, T=1024, D=64, H=128, gates=4H=512, fc head H->64->1.
//
// r10 post-mortem: weights finally resident (WRITE=2KB, VGPR 112+AGPR), but
// dur unchanged -> the per-step CRITICAL PATH was the limit: 2 barriers,
// a gl LDS round-trip (8-way conflicts), and an in-step x prefetch whose
// vmcnt(0) is drained at EVERY barrier (syncthreads semantics) = up to
// ~900 cyc HBM latency per step.
//
// THIS ROUND -- restructure the step dataflow:
//  (1) Wave w's 4 N-tiles = the 4 GATE CLASSES of units [16w,16w+16)
//      (gate = 128*nt + 16w + cc). After MFMA, each thread holds
//      gi/gf/gg/go of its 4 (row,unit) cells IN ACCUMULATORS: cell fully
//      in-register. gl buffer deleted, D-store deleted, barrier #1 deleted.
//      ONE barrier per step.
//  (2) x staged in 8-step chunks into a 16-slot LDS ring (issue loads at
//      top of t%8==0 step, ds_write at its end): the barrier vmcnt(0)
//      drain pays HBM latency once per 8 steps, not every step. A-frags
//      read x directly from the ring slot.
//
// 32 blocks x 512 threads (8 waves), block owns 16 batch rows.
// Weights: B-fragments staged via clobbered LDS (remat-proof, r9 fix kept:
// fully unrolled static indices), homed in AGPRs via "a"-constraint MFMA.

#define TT 1024
#define DD 64
#define HH 128
#define ROWS 16
#define HSTR 136    // hs row stride in f16 (272 B -> 2-way banks max)
#define XSTR 72     // xs row stride in f16 (144 B -> 2-way banks max)

typedef _Float16 f16x8 __attribute__((ext_vector_type(8)));
typedef float f32x4 __attribute__((ext_vector_type(4)));

// D = A*B + D, B fragment (weights) homed in AGPRs.
__device__ __forceinline__ void mfma_ab(f16x8 a, f16x8 b, f32x4& c) {
    asm("v_mfma_f32_16x16x32_f16 %0, %1, %2, %0"
        : "+v"(c)
        : "v"(a), "a"(b));
}

__device__ __forceinline__ float sigm(float x) {
    return 1.f / (1.f + __expf(-x));
}
__device__ __forceinline__ float tanh_f(float x) {
    return 1.f - 2.f / (__expf(2.f * x) + 1.f);
}

__device__ __forceinline__ f16x8 cvt8(float4 a, float4 b) {
    f16x8 f;
    f[0] = (_Float16)a.x; f[1] = (_Float16)a.y;
    f[2] = (_Float16)a.z; f[3] = (_Float16)a.w;
    f[4] = (_Float16)b.x; f[5] = (_Float16)b.y;
    f[6] = (_Float16)b.z; f[7] = (_Float16)b.w;
    return f;
}

__global__ __launch_bounds__(512)
__attribute__((amdgpu_waves_per_eu(2, 2)))
void lstm_mfma_kernel(const float* __restrict__ x_seq,
                      const float* __restrict__ W_ih,
                      const float* __restrict__ W_hh,
                      const float* __restrict__ b_ih,
                      const float* __restrict__ b_hh,
                      const float* __restrict__ W1v,
                      const float* __restrict__ b1v,
                      const float* __restrict__ W2v,
                      const float* __restrict__ b2v,
                      float* __restrict__ out)
{
    const int tid  = threadIdx.x;
    const int lane = tid & 63;
    const int w    = tid >> 6;        // wave 0..7
    const int p    = lane >> 4;       // k-group 0..3
    const int cc   = lane & 15;       // col/row within tile
    const int b0   = blockIdx.x * ROWS;

    __shared__ __align__(16) _Float16 hs[2][ROWS][HSTR];  // h double-buffer
    __shared__ __align__(16) _Float16 xs[16][ROWS][XSTR]; // x 16-slot ring

    // ============ weight staging through clobbered LDS (xs) ============
    // xs is rewritten by the x-ring during the t-loop -> fragment regs
    // cannot be rematerialized. Fully unrolled: all indices static (r9 fix).
    _Float16* wstage = &xs[0][0][0];   // [512][32] f16 = 32 KB (xs is 36 KB)

    f16x8 bf[4][6];
#pragma unroll
    for (int g = 0; g < 6; ++g) {
        const float* srcrow = (g < 4) ? (W_hh + tid * HH + 32 * g)
                                      : (W_ih + tid * DD + 32 * (g - 4));
        const float4* s4 = reinterpret_cast<const float4*>(srcrow);
        _Float16* dst = wstage + tid * 32;
#pragma unroll
        for (int c = 0; c < 2; ++c) {
            const float4 lo = s4[4 * c + 0], l1 = s4[4 * c + 1];
            const float4 h0 = s4[4 * c + 2], h1 = s4[4 * c + 3];
            *reinterpret_cast<f16x8*>(dst + 16 * c)     = cvt8(lo, l1);
            *reinterpret_cast<f16x8*>(dst + 16 * c + 8) = cvt8(h0, h1);
        }
        __syncthreads();
        // wave w owns the 4 GATE CLASSES of units [16w,16w+16):
        // bf[nt][g] = W[gate = 128*nt + 16*w + cc][k = 32g+8p+j]
#pragma unroll
        for (int nt = 0; nt < 4; ++nt) {
            const int gate = 128 * nt + 16 * w + cc;
            bf[nt][g] =
                *reinterpret_cast<const f16x8*>(wstage + gate * 32 + 8 * p);
        }
        __syncthreads();
    }
    // home fragments in AGPRs
#pragma unroll
    for (int nt = 0; nt < 4; ++nt)
#pragma unroll
        for (int g = 0; g < 6; ++g)
            asm("" : "+a"(bf[nt][g]));

    // bias via the same clobbered region
    float bias[4];
    {
        float* bstage = reinterpret_cast<float*>(&xs[0][0][0]);  // [512]
        bstage[tid] = b_ih[tid] + b_hh[tid];
        __syncthreads();
#pragma unroll
        for (int nt = 0; nt < 4; ++nt)
            bias[nt] = bstage[128 * nt + 16 * w + cc];
        __syncthreads();
    }
    // ===================================================================

    // ---- init: hs[0] = 0 ----
#pragma unroll
    for (int i = 0; i < 4; ++i) {
        const int idx = tid + 512 * i;          // 0..2047
        hs[0][idx >> 7][idx & 127] = (_Float16)0.f;
    }

    // ---- x-ring staging roles (fixed per thread) ----
    const int pr_pair = tid >> 2;               // 0..127 = (row, ts-offset)
    const int pr_row  = pr_pair >> 3;           // 0..15
    const int pr_tso  = pr_pair & 7;            // 0..7
    const int pr_q    = tid & 3;                // 16-float quarter

    // prologue: stage chunk [0,8) into slots 0..7
    {
        const float4* sp = reinterpret_cast<const float4*>(
            x_seq + ((size_t)(b0 + pr_row) * TT + pr_tso) * DD + pr_q * 16);
        const float4 v0 = sp[0], v1 = sp[1], v2 = sp[2], v3 = sp[3];
        _Float16* dst = &xs[pr_tso][pr_row][pr_q * 16];
        *reinterpret_cast<f16x8*>(dst)     = cvt8(v0, v1);
        *reinterpret_cast<f16x8*>(dst + 8) = cvt8(v2, v3);
    }

    const int u16 = 16 * w + cc;                // this thread's hidden unit
    float c0 = 0.f, c1 = 0.f, c2 = 0.f, c3 = 0.f;
    __syncthreads();

    for (int t = 0; t < TT; ++t) {
        const int cur = t & 1, nxt = cur ^ 1;

        // issue next-chunk global loads early (once per 8 steps)
        const bool stage = ((t & 7) == 0) && (t + 8 < TT);
        float4 s0, s1, s2, s3;
        if (stage) {
            const float4* sp = reinterpret_cast<const float4*>(
                x_seq + ((size_t)(b0 + pr_row) * TT + (t + 8 + pr_tso)) * DD +
                pr_q * 16);
            s0 = sp[0]; s1 = sp[1]; s2 = sp[2]; s3 = sp[3];
        }

        // ---- A-fragments: h from hs[cur], x from ring slot t&15 ----
        f16x8 a[6];
#pragma unroll
        for (int g = 0; g < 4; ++g)
            a[g] = *reinterpret_cast<const f16x8*>(&hs[cur][cc][32 * g + 8 * p]);
        {
            const _Float16* xrow = &xs[t & 15][cc][0];
            a[4] = *reinterpret_cast<const f16x8*>(xrow + 8 * p);
            a[5] = *reinterpret_cast<const f16x8*>(xrow + 32 + 8 * p);
        }

        // ---- MFMA: 4 gate-class chains, bias folded into acc init ----
        f32x4 acc[4];
#pragma unroll
        for (int nt = 0; nt < 4; ++nt)
            acc[nt] = (f32x4){bias[nt], bias[nt], bias[nt], bias[nt]};
#pragma unroll
        for (int g = 0; g < 6; ++g)
#pragma unroll
            for (int nt = 0; nt < 4; ++nt)
                mfma_ab(a[g], bf[nt][g], acc[nt]);

        // ---- cell fully in-register: acc[.][j] = row 4p+j, unit u16 ----
#define CELL(J, CREG)                                                        \
        {                                                                    \
            const float gi = acc[0][J], gf = acc[1][J];                      \
            const float gg = acc[2][J], go = acc[3][J];                      \
            CREG = sigm(gf) * CREG + sigm(gi) * tanh_f(gg);                  \
            hs[nxt][4 * p + J][u16] = (_Float16)(sigm(go) * tanh_f(CREG));   \
        }
        CELL(0, c0) CELL(1, c1) CELL(2, c2) CELL(3, c3)
#undef CELL

        // ---- ring write (once per 8 steps): slot for timestep t+8+tso ----
        if (stage) {
            _Float16* dst = &xs[(t + 8 + pr_tso) & 15][pr_row][pr_q * 16];
            *reinterpret_cast<f16x8*>(dst)     = cvt8(s0, s1);
            *reinterpret_cast<f16x8*>(dst + 8) = cvt8(s2, s3);
        }
        __syncthreads();   // the ONLY barrier per step
    }

    // ---- fused head: wave w -> rows 2w, 2w+1; lane = fc1 unit ----
#pragma unroll
    for (int rr = 0; rr < 2; ++rr) {
        const int r = 2 * w + rr;
        float z = b1v[lane];
        const float* w1 = W1v + lane * HH;
#pragma unroll 16
        for (int k = 0; k < HH; ++k)
            z = fmaf(w1[k], (float)hs[0][r][k], z);
        z = fmaxf(z, 0.f) * W2v[lane];
#pragma unroll
        for (int off = 32; off; off >>= 1)
            z += __shfl_down(z, off, 64);
        if (lane == 0) out[b0 + r] = z + b2v[0];
    }
}

extern "C" void kernel_launch(void* const* d_in, const int* in_sizes, int n_in,
                              void* d_out, int out_size, void* d_ws, size_t ws_size,
                              hipStream_t stream) {
    const float* x_seq = (const float*)d_in[0];
    const float* W_ih  = (const float*)d_in[1];
    const float* W_hh  = (const float*)d_in[2];
    const float* b_ih  = (const float*)d_in[3];
    const float* b_hh  = (const float*)d_in[4];
    const float* W1    = (const float*)d_in[5];
    const float* b1    = (const float*)d_in[6];
    const float* W2    = (const float*)d_in[7];
    const float* b2    = (const float*)d_in[8];
    float* out = (float*)d_out;

    lstm_mfma_kernel<<<32, 512, 0, stream>>>(
        x_seq, W_ih, W_hh, b_ih, b_hh, W1, b1, W2, b2, out);
}